// Round 18
// baseline (158.665 us; speedup 1.0000x reference)
//
#include <hip/hip_runtime.h>

#define NB 8
#define NN 256
#define NS 128
#define NM 8192
#define NK 200
#define KP1 201
#define FEPS 1e-9f
#define GROUP_BLOCKS (NB * NN)   // 2048 group units
#define CD1B_BLOCKS 128          // 512-thread blocks; 8 batches x 16 chunks
#define GRID_TOTAL (GROUP_BLOCKS + CD1B_BLOCKS)   // 2176
#define NT 512                   // threads per block (8 waves)
#define HBINS 2048

// ws layout (floats):
//  [0    .. 4096)  float2 per group unit {t1, t2}    (cd2 partials)
//  [4096 .. 6144)  float per group unit  cd1a        (cd1 term 1)
//  [6144 .. 6272)  float per cd1b block  t4          (cd1 term 2)
//  [6272]          unsigned completion counter (memset to 0 per launch)
#define CD1A_OFF (2 * GROUP_BLOCKS)
#define T4_OFF   (3 * GROUP_BLOCKS)
#define CNT_OFF  (3 * GROUP_BLOCKS + CD1B_BLOCKS)

// ---------- reduction helpers (512 threads = 8 waves) ----------
__device__ __forceinline__ float block_sum_f(float v, float* redf) {
    const int tid = threadIdx.x, w = tid >> 6, l = tid & 63;
    for (int o = 32; o; o >>= 1) v += __shfl_xor(v, o);
    if (l == 0) redf[w] = v;
    __syncthreads();
    float t = 0.0f;
#pragma unroll
    for (int j = 0; j < 8; ++j) t += redf[j];
    __syncthreads();
    return t;
}

__device__ __forceinline__ int block_excl_scan_i(int v, int* redi, int tid, int& total) {
    const int l = tid & 63, w = tid >> 6;
    int x = v;
    for (int o = 1; o < 64; o <<= 1) { int y = __shfl_up(x, o); if (l >= o) x += y; }
    if (l == 63) redi[w] = x;
    __syncthreads();
    int woff = 0, tot = 0;
#pragma unroll
    for (int j = 0; j < 8; ++j) { if (j < w) woff += redi[j]; tot += redi[j]; }
    total = tot;
    int ex = woff + x - v;
    __syncthreads();
    return ex;
}

__device__ __forceinline__ int find_bin(int* hist, int nbins, int& rem,
                                        int* redi, int* ibc, int tid) {
    const int C = nbins >> 9;            // bins per thread
    const int CC = C ? C : 1;
    const int base = tid * CC;
    int local = 0;
    for (int j = 0; j < CC; ++j) local += hist[base + j];
    int total;
    int ex = block_excl_scan_i(local, redi, tid, total);
    if (ex < rem && rem <= ex + local) {
        int run = ex;
        for (int j = 0; j < CC; ++j) {
            int h = hist[base + j];
            if (run + h >= rem) { ibc[0] = base + j; ibc[1] = rem - run; break; }
            run += h;
        }
    }
    __syncthreads();
    int bin = ibc[0]; rem = ibc[1];
    __syncthreads();
    return bin;
}

// ---------- single fused kernel; last finishing block writes out[0..2] ----------
__global__ __launch_bounds__(NT)        // natural allocation (clamps spill — R15)
void k_main(const float* __restrict__ means, const float* __restrict__ sp,
            const float* __restrict__ gt, float* __restrict__ ws,
            float* __restrict__ out) {
    __shared__ int   hist[HBINS];                 // 8KB; reused: rowred, cd1b mpool
    __shared__ float gx[NK], gy[NK], gz[NK], g2s[NK];
    __shared__ float sx[NS], sy[NS], sz[NS];
    __shared__ float redf[8];
    __shared__ int   redi[8];
    __shared__ int   ibc[2];
    __shared__ int   lastFlag;

    const int tid = threadIdx.x;
    const int w = tid >> 6, l = tid & 63;

    if (blockIdx.x >= GROUP_BLOCKS) {
        // ---- cd1 term 2: per (b,m) min over the 256 means; 512 m's per block ----
        const int blk = blockIdx.x - GROUP_BLOCKS;   // 0..127
        const int b = blk >> 4;
        const int m = ((blk & 15) << 9) + tid;
        float* mxs = (float*)hist;                   // 768 floats in 8KB pool
        float* mys = mxs + NN;
        float* mzs = mys + NN;
        const float* mb = means + (size_t)b * NN * 3;
        if (tid < NN) {
            mxs[tid] = mb[tid * 3 + 0];
            mys[tid] = mb[tid * 3 + 1];
            mzs[tid] = mb[tid * 3 + 2];
        }
        __syncthreads();
        const float* gp = gt + ((size_t)b * NM + m) * 3;
        const float px = gp[0], py = gp[1], pz = gp[2];
        float mn = 3.4e38f;
#pragma unroll 8
        for (int n = 0; n < NN; ++n) {
            float dx = px - mxs[n], dy = py - mys[n], dz = pz - mzs[n];
            mn = fminf(mn, fmaf(dx, dx, fmaf(dy, dy, dz * dz)));
        }
        float d2 = sqrtf(fmaxf(mn, FEPS));
        float t4 = block_sum_f(d2, redf);
        if (tid == 0) atomicExch(&ws[T4_OFF + blk], t4);
    } else {
        // ---- group path: one block per (b,n) ----
        const int bn = blockIdx.x;
        const int b  = bn >> 8;

        const float* spb = sp + (size_t)bn * NS * 3;
        if (tid < NS) {
            sx[tid] = spb[tid * 3 + 0];
            sy[tid] = spb[tid * 3 + 1];
            sz[tid] = spb[tid * 3 + 2];
        }
        const float mx = means[bn * 3 + 0];
        const float my = means[bn * 3 + 1];
        const float mz = means[bn * 3 + 2];
        const float* g = gt + (size_t)b * NM * 3;

        // distances: contiguous float4 loads; thread owns m in [tid*16, tid*16+16)
        const float* gtb = g + tid * 48;
        float vd[16];
        float vmin = 3.4e38f; int varg = -1;
#pragma unroll 2
        for (int c = 0; c < 4; ++c) {
            float4 f0 = *(const float4*)(gtb + c * 12);
            float4 f1 = *(const float4*)(gtb + c * 12 + 4);
            float4 f2 = *(const float4*)(gtb + c * 12 + 8);
            float px[4] = {f0.x, f0.w, f1.z, f2.y};
            float py[4] = {f0.y, f1.x, f1.w, f2.z};
            float pz[4] = {f0.z, f1.y, f2.x, f2.w};
#pragma unroll
            for (int j = 0; j < 4; ++j) {
                int i = c * 4 + j;
                float dx = mx - px[j], dy = my - py[j], dz = mz - pz[j];
                float d = fmaf(dx, dx, fmaf(dy, dy, dz * dz));
                vd[i] = d;
                if (d < vmin) { vmin = d; varg = tid * 16 + i; }
            }
        }

        // block argmin (value,index), lowest index on ties
        for (int o = 32; o; o >>= 1) {
            float ov = __shfl_xor(vmin, o);
            int   oi = __shfl_xor(varg, o);
            if (ov < vmin || (ov == vmin && oi < varg)) { vmin = ov; varg = oi; }
        }
        if (l == 0) { redf[w] = vmin; redi[w] = varg; }
        __syncthreads();
        float dmin = redf[0]; int m0 = redi[0];
#pragma unroll
        for (int i = 1; i < 8; ++i) {
            if (redf[i] < dmin || (redf[i] == dmin && redi[i] < m0)) { dmin = redf[i]; m0 = redi[i]; }
        }
        if (tid == 0) atomicExch(&ws[CD1A_OFF + bn], sqrtf(fmaxf(dmin, FEPS)));
        __syncthreads();

        // exact 201st-smallest via 3-level histogram radix
        int rem = KP1;
        unsigned prefix;
        for (int j = tid; j < HBINS; j += NT) hist[j] = 0;
        __syncthreads();
#pragma unroll
        for (int i = 0; i < 16; ++i) atomicAdd(&hist[__float_as_uint(vd[i]) >> 20], 1);
        __syncthreads();
        prefix = (unsigned)find_bin(hist, 2048, rem, redi, ibc, tid);
        for (int j = tid; j < HBINS; j += NT) hist[j] = 0;
        __syncthreads();
#pragma unroll
        for (int i = 0; i < 16; ++i) {
            unsigned u = __float_as_uint(vd[i]);
            if ((u >> 20) == prefix) atomicAdd(&hist[(u >> 9) & 2047], 1);
        }
        __syncthreads();
        prefix = (prefix << 11) | (unsigned)find_bin(hist, 2048, rem, redi, ibc, tid);
        for (int j = tid; j < 512; j += NT) hist[j] = 0;
        __syncthreads();
#pragma unroll
        for (int i = 0; i < 16; ++i) {
            unsigned u = __float_as_uint(vd[i]);
            if ((u >> 9) == prefix) atomicAdd(&hist[u & 511], 1);
        }
        __syncthreads();
        const unsigned X = (prefix << 9) | (unsigned)find_bin(hist, 512, rem, redi, ibc, tid);

        // gather: strict-less via scan, ties fill; |g|^2 into LDS
        int c = 0;
#pragma unroll
        for (int i = 0; i < 16; ++i) {
            int m = tid * 16 + i;
            c += (m != m0 && __float_as_uint(vd[i]) < X);
        }
        int total;
        int p = block_excl_scan_i(c, redi, tid, total);
#pragma unroll
        for (int i = 0; i < 16; ++i) {
            int m = tid * 16 + i;
            if (m != m0 && __float_as_uint(vd[i]) < X) {
                float x = g[m * 3 + 0], y = g[m * 3 + 1], z = g[m * 3 + 2];
                gx[p] = x; gy[p] = y; gz[p] = z;
                g2s[p] = fmaf(x, x, fmaf(y, y, z * z));
                ++p;
            }
        }
        if (tid == 0) ibc[0] = total;
        __syncthreads();
#pragma unroll
        for (int i = 0; i < 16; ++i) {
            int m = tid * 16 + i;
            if (m != m0 && __float_as_uint(vd[i]) == X) {
                int q = atomicAdd(&ibc[0], 1);
                if (q < NK) {
                    float x = g[m * 3 + 0], y = g[m * 3 + 1], z = g[m * 3 + 2];
                    gx[q] = x; gy[q] = y; gz[q] = z;
                    g2s[q] = fmaf(x, x, fmaf(y, y, z * z));
                }
            }
        }
        __syncthreads();

        // fused chamfer via d = |s|^2 + |g|^2 - 2 s.g
        // thread (ts, tk) = (tid&31, tid>>5): 4 s-rows in regs x 16 k-col slots.
        const int ts = tid & 31, tk = tid >> 5;
        float psx[4], psy[4], psz[4], s2[4];
#pragma unroll
        for (int j = 0; j < 4; ++j) {
            int s = ts * 4 + j;
            float x = sx[s], y = sy[s], z = sz[s];
            s2[j] = fmaf(x, x, fmaf(y, y, z * z));
            psx[j] = -2.0f * x; psy[j] = -2.0f * y; psz[j] = -2.0f * z;
        }
        float rowacc[4];
#pragma unroll
        for (int j = 0; j < 4; ++j) rowacc[j] = 3.4e38f;
        float d2acc = 0.0f;
#pragma unroll 4
        for (int ip = 0; ip < 12; ++ip) {
            int k = tk + 16 * ip;
            float qx = gx[k], qy = gy[k], qz = gz[k], hg = g2s[k];
            float cm = 3.4e38f;
#pragma unroll
            for (int j = 0; j < 4; ++j) {
                float f = fmaf(psx[j], qx, fmaf(psy[j], qy, psz[j] * qz));
                rowacc[j] = fminf(rowacc[j], hg + f);
                cm = fminf(cm, s2[j] + f);
            }
            cm = fminf(cm, __shfl_xor(cm, 1));
            cm = fminf(cm, __shfl_xor(cm, 2));
            cm = fminf(cm, __shfl_xor(cm, 4));
            cm = fminf(cm, __shfl_xor(cm, 8));
            cm = fminf(cm, __shfl_xor(cm, 16));
            if (ts == 0) d2acc += sqrtf(fmaxf(hg + cm, FEPS));
        }
        if (tk < 8) {
            int k = 192 + tk;
            float qx = gx[k], qy = gy[k], qz = gz[k], hg = g2s[k];
            float cm = 3.4e38f;
#pragma unroll
            for (int j = 0; j < 4; ++j) {
                float f = fmaf(psx[j], qx, fmaf(psy[j], qy, psz[j] * qz));
                rowacc[j] = fminf(rowacc[j], hg + f);
                cm = fminf(cm, s2[j] + f);
            }
            cm = fminf(cm, __shfl_xor(cm, 1));
            cm = fminf(cm, __shfl_xor(cm, 2));
            cm = fminf(cm, __shfl_xor(cm, 4));
            cm = fminf(cm, __shfl_xor(cm, 8));
            cm = fminf(cm, __shfl_xor(cm, 16));
            if (ts == 0) d2acc += sqrtf(fmaxf(hg + cm, FEPS));
        }
#pragma unroll
        for (int j = 0; j < 4; ++j) {
            rowacc[j] = fminf(rowacc[j], __shfl_xor(rowacc[j], 32));
            rowacc[j] += s2[j];
        }
        float* rowred = (float*)hist;   // reuse hist LDS: [8][128] floats
        if (l < 32) {
#pragma unroll
            for (int j = 0; j < 4; ++j) rowred[w * NS + l * 4 + j] = rowacc[j];
        }
        __syncthreads();
        float d1v = 0.0f;
        if (tid < NS) {
            float m = rowred[tid];
#pragma unroll
            for (int j = 1; j < 8; ++j) m = fminf(m, rowred[j * NS + tid]);
            d1v = sqrtf(fmaxf(m, FEPS));
        }
        float t1 = block_sum_f(d1v, redf);
        float t2 = block_sum_f(d2acc, redf);
        if (tid == 0) {
            atomicExch(&ws[2 * bn], t1);
            atomicExch(&ws[2 * bn + 1], t2);
        }
    }

    // ---- epilogue: tid0-only fence + counter; last block reduces ----
    if (tid == 0) {
        __threadfence();                               // order exch's before counter
        unsigned old = atomicAdd((unsigned*)(ws + CNT_OFF), 1u);
        lastFlag = (old == GRID_TOTAL - 1);
        if (lastFlag) __threadfence();                 // acquire before reads
    }
    __syncthreads();
    if (lastFlag) {
        float s1 = 0.0f, s2v = 0.0f, s3 = 0.0f, s4 = 0.0f;
#pragma unroll
        for (int j = 0; j < GROUP_BLOCKS / NT; ++j) {  // 4 iterations
            int idx = tid + j * NT;
            s1 += atomicAdd(&ws[2 * idx], 0.0f);       // coherent read
            s2v += atomicAdd(&ws[2 * idx + 1], 0.0f);
            s3 += atomicAdd(&ws[CD1A_OFF + idx], 0.0f);
        }
        if (tid < CD1B_BLOCKS) s4 = atomicAdd(&ws[T4_OFF + tid], 0.0f);
        float t1 = block_sum_f(s1, redf);
        float t2 = block_sum_f(s2v, redf);
        float t3 = block_sum_f(s3, redf);
        float t4 = block_sum_f(s4, redf);
        if (tid == 0) {
            float cd2 = 0.5f * (t1 / ((float)NB * NS) + t2 / ((float)NB * NK));
            float cd1 = 0.5f * (t3 / ((float)NB * NN) + t4 / ((float)NB * NM));
            out[0] = cd2 * 1000.0f;
            out[1] = cd1 * 1000.0f;
            out[2] = cd2 * 1000.0f;
        }
    }
}

extern "C" void kernel_launch(void* const* d_in, const int* in_sizes, int n_in,
                              void* d_out, int out_size, void* d_ws, size_t ws_size,
                              hipStream_t stream) {
    const float* means = (const float*)d_in[0];
    const float* sp    = (const float*)d_in[1];
    const float* gt    = (const float*)d_in[2];
    float* out = (float*)d_out;
    float* ws  = (float*)d_ws;

    hipMemsetAsync(ws + CNT_OFF, 0, sizeof(unsigned), stream);
    k_main<<<GRID_TOTAL, NT, 0, stream>>>(means, sp, gt, ws, out);
}